// Round 10
// baseline (268.633 us; speedup 1.0000x reference)
//
#include <hip/hip_runtime.h>
#include <math.h>

// Problem constants
#define BB 32
#define NN 1024
#define DD 768
#define KK 512
#define MM (BB * NN)  // 32768 token rows

typedef _Float16 half8 __attribute__((ext_vector_type(8)));
typedef _Float16 half4 __attribute__((ext_vector_type(4)));
typedef float floatx4 __attribute__((ext_vector_type(4)));

// async global(16B) -> LDS, per-lane dest = uniform base + lane*16
__device__ __forceinline__ void load_lds16(const void* g, void* l) {
    __builtin_amdgcn_global_load_lds(
        (const __attribute__((address_space(1))) unsigned int*)g,
        (__attribute__((address_space(3))) unsigned int*)l, 16, 0, 0);
}

__device__ __forceinline__ void memfence() { asm volatile("" ::: "memory"); }

__device__ __forceinline__ void cvt_store8(float4 a, float4 b, _Float16* dst) {
    half8 h;
    h[0] = (_Float16)a.x; h[1] = (_Float16)a.y; h[2] = (_Float16)a.z; h[3] = (_Float16)a.w;
    h[4] = (_Float16)b.x; h[5] = (_Float16)b.y; h[6] = (_Float16)b.z; h[7] = (_Float16)b.w;
    *(half8*)dst = h;
}

// ---------------------------------------------------------------------------
// Codebook prep (merged): fp32->fp16 cast + csq[k] = sum_d cb[k][d]^2
// ---------------------------------------------------------------------------
__global__ __launch_bounds__(256) void prep_codebook(const float* __restrict__ cb,
                                                     _Float16* __restrict__ Cbh,
                                                     float* __restrict__ csq) {
    int k = blockIdx.x;
    const float* row = cb + (size_t)k * DD;
    _Float16* orow = Cbh + (size_t)k * DD;
    float s = 0.f;
    for (int d = threadIdx.x; d < DD; d += 256) {
        float v = row[d];
        s += v * v;
        orow[d] = (_Float16)v;
    }
    #pragma unroll
    for (int off = 32; off > 0; off >>= 1) s += __shfl_down(s, off);
    __shared__ float sm[4];
    int lane = threadIdx.x & 63, wid = threadIdx.x >> 6;
    if (lane == 0) sm[wid] = s;
    __syncthreads();
    if (threadIdx.x == 0) csq[k] = sm[0] + sm[1] + sm[2] + sm[3];
}

// ---------------------------------------------------------------------------
// FUSED v10: logits + softmax + St + Xt. 1024 threads (16 waves), 64 tokens,
// per-wave tile 64 tokens x 32 k (wk = w*32, ki<2).
// TRIPLE-buffered Cs/Xs, stage round it+2 during iter it, barrier drains only
// round it+1 (counted vmcnt keeps the newest round in flight -> ~2 iterations
// of dma-latency cover; R8 proved drain-per-iter dbuf leaves ~5x exposed).
// Per-thread per-iter VMEM ops are role-uniform, so counts are exact:
//   w<4: [dma,dma, Xload,Xload, XtStore]=5 -> vmcnt(5)
//   w4-7: [dma,dma, XtStore]=3            -> vmcnt(3)
//   w>=8: [dma,dma]=2                     -> vmcnt(2)
// Tail (it>=20) uses vmcnt(0) (3 full drains, negligible).
// XOR swizzle + lds-dma pre-swizzled source + R3's store-coalesced Xt gather
// (its ~5.5M conflict cycles are hidden; R7 proved the alternative costs 15us).
// ---------------------------------------------------------------------------
__global__ __launch_bounds__(1024, 4) void fused_logits_softmax(
    const float* __restrict__ X,        // [M, D] fp32
    const _Float16* __restrict__ Cbh,   // [K, D] fp16
    const float* __restrict__ csq,      // [K]
    _Float16* __restrict__ St,          // [B, K, N] fp16
    _Float16* __restrict__ Xt)          // [B, D, N] fp16
{
    __shared__ _Float16 Cs[3][512][32];   // 96 KB triple-buffered codebook chunk
    __shared__ _Float16 Xs[3][64][32];    // 12 KB triple-buffered token chunk
    __shared__ float redbuf[16][64];      // per-wave softmax partials
    __shared__ float gred[64];            // reduced per-token value

    const int t = threadIdx.x;          // 0..1023
    const int w = t >> 6;               // 0..15
    const int lane = t & 63;
    const int l15 = lane & 15;
    const int quad = lane >> 4;
    const int wk = w * 32;              // this wave's k slab (32 wide)
    const int gm0 = blockIdx.x * 64;    // global token base
    const int b = gm0 >> 10;
    const int n0 = gm0 & 1023;

    const int qs = (quad ^ ((l15 >> 1) & 3)) * 8;

    float cs[2];
    #pragma unroll
    for (int ki = 0; ki < 2; ki++) cs[ki] = csq[wk + ki * 16 + l15];

    floatx4 acc[4][2] = {};

    // Cs staging: 1024 threads x 2 units; unit u=c*1024+t -> row=c*256+(t>>2),
    // phys q=t&3, source col-chunk cq=(t&3)^((t>>3)&3)
    const int cr = t >> 2;
    const int cq = (t & 3) ^ ((t >> 3) & 3);
    // X staging: t<256, row cr (0..63), 2 float4 -> half8 at phys unit (t&3)
    const float* xsrc = X + (size_t)(gm0 + cr) * DD + cq * 8;

    // Xt gather map (R3, store-coalesced): t<512: d = t>>4, n base = (t&15)*4
    const int tdr = t >> 4;
    const int tn4 = (t & 15) * 4;

    // ---- prologue: rounds 0,1 staged; X reg queue = chunks 2,3 ----
    float4 pca, pcb, pna, pnb;
    if (t < 256) {
        float4 a0 = *(const float4*)xsrc;
        float4 b0 = *(const float4*)(xsrc + 4);
        float4 a1 = *(const float4*)(xsrc + 32);
        float4 b1 = *(const float4*)(xsrc + 36);
        cvt_store8(a0, b0, &Xs[0][cr][(t & 3) * 8]);
        cvt_store8(a1, b1, &Xs[1][cr][(t & 3) * 8]);
    }
    #pragma unroll
    for (int c = 0; c < 2; c++)
        load_lds16(Cbh + (size_t)(c * 256 + cr) * DD + cq * 8,
                   (_Float16*)Cs[0] + (c * 1024 + t) * 8);
    memfence();
    #pragma unroll
    for (int c = 0; c < 2; c++)
        load_lds16(Cbh + (size_t)(c * 256 + cr) * DD + 32 + cq * 8,
                   (_Float16*)Cs[1] + (c * 1024 + t) * 8);
    memfence();
    if (t < 256) {
        pca = *(const float4*)(xsrc + 64);   // chunk 2
        pcb = *(const float4*)(xsrc + 68);
        pna = *(const float4*)(xsrc + 96);   // chunk 3
        pnb = *(const float4*)(xsrc + 100);
    }
    // barrier: round0 complete. w<4 queue: [dma0 x2, dma1 x2, X2 x2, X3 x2]
    if (w < 4) asm volatile("s_waitcnt vmcnt(6) lgkmcnt(0)" ::: "memory");
    else       asm volatile("s_waitcnt vmcnt(2) lgkmcnt(0)" ::: "memory");
    __builtin_amdgcn_s_barrier();

    int cur = 0;                         // = it % 3
    for (int it = 0; it < 24; ++it) {
        const int d0 = it * 32;
        const int nxt = (cur == 2) ? 0 : cur + 1;
        const int nx2 = (nxt == 2) ? 0 : nxt + 1;  // (it+2)%3
        // ---- stage round it+2 (dma + conversion), prefetch chunk it+4 ----
        if (it + 2 < 24) {
            const int d0s = d0 + 64;
            #pragma unroll
            for (int c = 0; c < 2; c++)
                load_lds16(Cbh + (size_t)(c * 256 + cr) * DD + d0s + cq * 8,
                           (_Float16*)Cs[nx2] + (c * 1024 + t) * 8);
            memfence();
            if (t < 256) {
                cvt_store8(pca, pcb, &Xs[nx2][cr][(t & 3) * 8]);
                pca = pna; pcb = pnb;
                if (it + 4 < 24) {
                    pna = *(const float4*)(xsrc + (it + 4) * 32);
                    pnb = *(const float4*)(xsrc + (it + 4) * 32 + 4);
                }
                memfence();
            }
        }
        // ---- Xt write-back of current chunk: LDS gather + half4 store ----
        if (t < 512) {
            half4 xo;
            #pragma unroll
            for (int j = 0; j < 4; j++) {
                int n = tn4 + j;
                xo[j] = *((const _Float16*)Xs[cur] + n * 32 +
                          (((tdr >> 3) ^ ((n >> 1) & 3)) << 3) + (tdr & 7));
            }
            *(half4*)&Xt[((size_t)b * DD + d0 + tdr) * NN + n0 + tn4] = xo;
        }
        // ---- fragments + MFMA on buffer cur ----
        half8 af[4], bf[2];
        #pragma unroll
        for (int mi = 0; mi < 4; mi++)
            af[mi] = *(half8*)((_Float16*)Xs[cur] + (mi * 16 + l15) * 32 + qs);
        #pragma unroll
        for (int ki = 0; ki < 2; ki++)
            bf[ki] = *(half8*)((_Float16*)Cs[cur] + (wk + ki * 16 + l15) * 32 + qs);
        #pragma unroll
        for (int mi = 0; mi < 4; mi++)
            #pragma unroll
            for (int ki = 0; ki < 2; ki++)
                acc[mi][ki] = __builtin_amdgcn_mfma_f32_16x16x32_f16(af[mi], bf[ki], acc[mi][ki], 0, 0, 0);
        // ---- counted barrier: drain round it+1, keep round it+2 in flight ----
        if (it + 1 < 24) {
            if (it < 20) {
                if (w < 4)      asm volatile("s_waitcnt vmcnt(5) lgkmcnt(0)" ::: "memory");
                else if (w < 8) asm volatile("s_waitcnt vmcnt(3) lgkmcnt(0)" ::: "memory");
                else            asm volatile("s_waitcnt vmcnt(2) lgkmcnt(0)" ::: "memory");
            } else {
                asm volatile("s_waitcnt vmcnt(0) lgkmcnt(0)" ::: "memory");
            }
            __builtin_amdgcn_s_barrier();
            cur = nxt;
        }
    }

    // ---- softmax over k=512 ----
    // logit = 2*acc - cs;  k = wk + ki*16 + l15, token = mi*16 + quad*4 + r
    float pmax[4][4];
    #pragma unroll
    for (int mi = 0; mi < 4; mi++)
        #pragma unroll
        for (int r = 0; r < 4; r++) {
            float m = -1e30f;
            #pragma unroll
            for (int ki = 0; ki < 2; ki++)
                m = fmaxf(m, 2.f * acc[mi][ki][r] - cs[ki]);
            pmax[mi][r] = m;
        }
    #pragma unroll
    for (int off = 1; off < 16; off <<= 1)
        #pragma unroll
        for (int mi = 0; mi < 4; mi++)
            #pragma unroll
            for (int r = 0; r < 4; r++)
                pmax[mi][r] = fmaxf(pmax[mi][r], __shfl_xor(pmax[mi][r], off));
    if (l15 == 0) {
        #pragma unroll
        for (int mi = 0; mi < 4; mi++)
            #pragma unroll
            for (int r = 0; r < 4; r++)
                redbuf[w][mi * 16 + quad * 4 + r] = pmax[mi][r];
    }
    __syncthreads();
    if (t < 64) {
        float g = redbuf[0][t];
        #pragma unroll
        for (int wv = 1; wv < 16; wv++) g = fmaxf(g, redbuf[wv][t]);
        gred[t] = g;
    }
    __syncthreads();
    float gmax[4][4];
    #pragma unroll
    for (int mi = 0; mi < 4; mi++)
        #pragma unroll
        for (int r = 0; r < 4; r++)
            gmax[mi][r] = gred[mi * 16 + quad * 4 + r];   // broadcast read
    __syncthreads();   // redbuf/gred reuse below

    float psum[4][4] = {};
    #pragma unroll
    for (int mi = 0; mi < 4; mi++)
        #pragma unroll
        for (int ki = 0; ki < 2; ki++) {
            floatx4 e;
            #pragma unroll
            for (int r = 0; r < 4; r++) {
                e[r] = __expf(2.f * acc[mi][ki][r] - cs[ki] - gmax[mi][r]);
                psum[mi][r] += e[r];
            }
            acc[mi][ki] = e;
        }
    #pragma unroll
    for (int off = 1; off < 16; off <<= 1)
        #pragma unroll
        for (int mi = 0; mi < 4; mi++)
            #pragma unroll
            for (int r = 0; r < 4; r++)
                psum[mi][r] += __shfl_xor(psum[mi][r], off);
    if (l15 == 0) {
        #pragma unroll
        for (int mi = 0; mi < 4; mi++)
            #pragma unroll
            for (int r = 0; r < 4; r++)
                redbuf[w][mi * 16 + quad * 4 + r] = psum[mi][r];
    }
    __syncthreads();
    if (t < 64) {
        float s = redbuf[0][t];
        #pragma unroll
        for (int wv = 1; wv < 16; wv++) s += redbuf[wv][t];
        gred[t] = 1.f / s;
    }
    __syncthreads();
    float ginv[4][4];
    #pragma unroll
    for (int mi = 0; mi < 4; mi++)
        #pragma unroll
        for (int r = 0; r < 4; r++)
            ginv[mi][r] = gred[mi * 16 + quad * 4 + r];

    // scale + transposed store: St[b][k][n]
    #pragma unroll
    for (int mi = 0; mi < 4; mi++)
        #pragma unroll
        for (int ki = 0; ki < 2; ki++) {
            half4 s4;
            #pragma unroll
            for (int r = 0; r < 4; r++)
                s4[r] = (_Float16)(acc[mi][ki][r] * ginv[mi][r]);
            int k = wk + ki * 16 + l15;
            *(half4*)&St[((size_t)b * KK + k) * NN + n0 + mi * 16 + quad * 4] = s4;
        }
}

// ---------------------------------------------------------------------------
// GEMM2 v8: out[b][k][d] = sum_n St[b][k][n] * Xt[b][d][n]
// 128x128 tile, BK=32. TRIPLE-buffered LDS (48 KB -> 3 blocks/CU), stage
// round it+2 during iter it, barrier vmcnt(4) drains only round it+1 (keeps
// the newest 4 dma in flight -> ~2 iters of latency cover). XCD swizzle kept.
// ---------------------------------------------------------------------------
__global__ __launch_bounds__(256, 3) void gemm2_mfma(const _Float16* __restrict__ St,
                                                     const _Float16* __restrict__ Xt,
                                                     float* __restrict__ out) {
    __shared__ _Float16 As[3][128][32];  // 24 KB
    __shared__ _Float16 Bs[3][128][32];  // 24 KB

    // bijective XCD swizzle over 768 blocks (768 % 8 == 0)
    const int lin = blockIdx.x;
    const int wg = (lin & 7) * 96 + (lin >> 3);
    const int b = wg / 24;
    const int rr = wg % 24;
    const int k0 = (rr / 6) * 128;
    const int d0 = (rr % 6) * 128;

    const int t = threadIdx.x;
    const int wave = t >> 6;
    const int lane = t & 63;
    const int wm = (wave >> 1) * 64;
    const int wn = (wave & 1) * 64;
    const int l15 = lane & 15;
    const int quad = lane >> 4;
    const int qs = (quad ^ ((l15 >> 1) & 3)) * 8;

    const int cr = t >> 2;                       // row within 64-row group
    const int cq = (t & 3) ^ ((t >> 3) & 3);     // swizzled source col-chunk

    floatx4 acc[4][4] = {};

    const _Float16* Abase = St + ((size_t)b * KK + k0) * NN;
    const _Float16* Bbase = Xt + ((size_t)b * DD + d0) * NN;

    // prologue: stage rounds 0,1
    #pragma unroll
    for (int c = 0; c < 2; c++) {
        load_lds16(Abase + (size_t)(c * 64 + cr) * NN + cq * 8,
                   (_Float16*)As[0] + (c * 256 + t) * 8);
        load_lds16(Bbase + (size_t)(c * 64 + cr) * NN + cq * 8,
                   (_Float16*)Bs[0] + (c * 256 + t) * 8);
    }
    memfence();
    #pragma unroll
    for (int c = 0; c < 2; c++) {
        load_lds16(Abase + (size_t)(c * 64 + cr) * NN + 32 + cq * 8,
                   (_Float16*)As[1] + (c * 256 + t) * 8);
        load_lds16(Bbase + (size_t)(c * 64 + cr) * NN + 32 + cq * 8,
                   (_Float16*)Bs[1] + (c * 256 + t) * 8);
    }
    memfence();
    asm volatile("s_waitcnt vmcnt(4)" ::: "memory");   // round 0 complete
    __builtin_amdgcn_s_barrier();

    int cur = 0;
    for (int it = 0; it < 32; ++it) {
        const int nxt = (cur == 2) ? 0 : cur + 1;
        const int nx2 = (nxt == 2) ? 0 : nxt + 1;
        if (it + 2 < 32) {
            const int n0s = (it + 2) * 32;
            #pragma unroll
            for (int c = 0; c < 2; c++) {
                load_lds16(Abase + (size_t)(c * 64 + cr) * NN + n0s + cq * 8,
                           (_Float16*)As[nx2] + (c * 256 + t) * 8);
                load_lds16(Bbase + (size_t)(c * 64 + cr) * NN + n0s + cq * 8,
                           (_Float16*)Bs[nx2] + (c * 256 + t) * 8);
            }
            memfence();
        }
        half8 af[4], bf[4];
        #pragma unroll
        for (int i = 0; i < 4; i++)
            af[i] = *(half8*)((_Float16*)As[cur] + (wm + i * 16 + l15) * 32 + qs);
        #pragma unroll
        for (int i = 0; i < 4; i++)
            bf[i] = *(half8*)((_Float16*)Bs[cur] + (wn + i * 16 + l15) * 32 + qs);
        #pragma unroll
        for (int mi = 0; mi < 4; mi++)
            #pragma unroll
            for (int ni = 0; ni < 4; ni++)
                acc[mi][ni] = __builtin_amdgcn_mfma_f32_16x16x32_f16(af[mi], bf[ni], acc[mi][ni], 0, 0, 0);
        if (it + 1 < 32) {
            if (it < 30) asm volatile("s_waitcnt vmcnt(4) lgkmcnt(0)" ::: "memory");
            else         asm volatile("s_waitcnt vmcnt(0) lgkmcnt(0)" ::: "memory");
            __builtin_amdgcn_s_barrier();
            cur = nxt;
        }
    }

    #pragma unroll
    for (int ni = 0; ni < 4; ni++) {
        #pragma unroll
        for (int mi = 0; mi < 4; mi++) {
            int k = k0 + wm + mi * 16 + quad * 4;
            int d = d0 + wn + ni * 16 + l15;
            float* op = out + ((size_t)b * KK + k) * DD + d;
            floatx4 a = acc[mi][ni];
            op[0 * DD] = a[0];
            op[1 * DD] = a[1];
            op[2 * DD] = a[2];
            op[3 * DD] = a[3];
        }
    }
}

// ---------------------------------------------------------------------------
extern "C" void kernel_launch(void* const* d_in, const int* in_sizes, int n_in,
                              void* d_out, int out_size, void* d_ws, size_t ws_size,
                              hipStream_t stream) {
    const float* x  = (const float*)d_in[0];   // [B,N,D] fp32
    const float* cb = (const float*)d_in[1];   // [K,D] fp32
    float* out = (float*)d_out;                // [B,K,D] fp32

    char* ws = (char*)d_ws;
    float*    csq = (float*)ws;                                   // 4 KB
    _Float16* Cbh = (_Float16*)(ws + 4096);                       // 768 KB
    _Float16* Xt  = (_Float16*)(ws + 4096 + 786432);              // 48 MB [b][d][n]
    _Float16* St  = (_Float16*)(ws + 4096 + 786432 + 50331648);   // 32 MB [b][k][n]

    // codebook prep (merged cast + csq)
    prep_codebook<<<KK, 256, 0, stream>>>(cb, Cbh, csq);

    // fused logits + softmax -> St (fp16 [b][k][n]) AND X transpose -> Xt
    fused_logits_softmax<<<MM / 64, 1024, 0, stream>>>(x, Cbh, csq, St, Xt);

    // aggregate (b-major + XCD swizzle)
    gemm2_mfma<<<768, 256, 0, stream>>>(St, Xt, out);
}